// Round 11
// baseline (217.781 us; speedup 1.0000x reference)
//
#include <hip/hip_runtime.h>

#define N_NODES 50000
#define N_EDGES 800000
#define D 128
#define ROWS 16
#define BCAP 255         // slot cap within a row's 512B out budget (deg max ~40)
#define LCAP 64          // LDS-staged slots per row, power of 2 (P(deg>64) ~ 0)
#define EDGE_BLOCKS 782  // ceil(200000/256) edge quads
#define XCONV_BLOCKS 3125 // 3125*256*8 = 6.4M floats = x converted to bf16
#define NORM_BLOCKS 196  // 196*256 = 50176 >= 50000
#define WSPLIT_BLOCKS 128 // 128*256 = 32768 = 2*D*D
#define XB_OFF 200064    // xb offset in d_ws (16B aligned, past deg)
#define WS_NEEDED 13000064ull

typedef int   v4i __attribute__((ext_vector_type(4)));
typedef float v4f __attribute__((ext_vector_type(4)));

// Buffer map:
//  d_ws [0, 200000)   : deg (int[50000]) — single-pass cursor == final in-degree
//  d_ws [200064, +12.8M) : xb (bf16 copy of x)  — ONLY if ws_size >= WS_NEEDED
//  d_out              : per-row 512B: scatter writes src ids (ushort[<=BCAP]);
//                       fused reads ONLY ITS OWN rows' slots, then overwrites
//                       them with output => no cross-block hazard.
//  dstbuf (dead after scatter consumes dst):
//    [0, 200000)        : normArr; [200000, +131072): whi1/wlo1/whi2/wlo2
// Round-9 lesson: MFMA B operands come from MEMORY loads only (waitcnt slack).

// ---- round-to-nearest-even f32 -> bf16 helpers ------------------------------
__device__ __forceinline__ unsigned short bf_rne(float v) {
    unsigned u = __float_as_uint(v);
    u += 0x7FFFu + ((u >> 16) & 1u);
    return (unsigned short)(u >> 16);
}
__device__ __forceinline__ float bf_up(unsigned short h) {
    return __uint_as_float((unsigned)h << 16);
}
__device__ __forceinline__ void split_pack(float a, float b, unsigned& hw, unsigned& lw) {
    unsigned short ha = bf_rne(a);
    unsigned short hb = bf_rne(b);
    unsigned short la = bf_rne(a - bf_up(ha));
    unsigned short lb = bf_rne(b - bf_up(hb));
    hw = (unsigned)ha | ((unsigned)hb << 16);
    lw = (unsigned)la | ((unsigned)lb << 16);
}
__device__ __forceinline__ unsigned pack2(float a, float b) {
    return (unsigned)bf_rne(a) | ((unsigned)bf_rne(b) << 16);
}

// ---- K1: single-pass slot scatter + (big path) x -> bf16 conversion ---------
__global__ void scatter_kernel(const int4* __restrict__ src4,
                               const int4* __restrict__ dst4,
                               int* __restrict__ deg,
                               unsigned short* outSlots,     // = (ushort*)d_out
                               const float* __restrict__ x,
                               unsigned short* __restrict__ xb) {
    int b = blockIdx.x, t = threadIdx.x;
    if (b < EDGE_BLOCKS) {
        int e = b * 256 + t;
        if (e < N_EDGES / 4) {
            int4 s = src4[e];
            int4 d = dst4[e];
            int p;
            p = atomicAdd(&deg[d.x], 1); if (p < BCAP) outSlots[(size_t)d.x * 256 + p] = (unsigned short)s.x;
            p = atomicAdd(&deg[d.y], 1); if (p < BCAP) outSlots[(size_t)d.y * 256 + p] = (unsigned short)s.y;
            p = atomicAdd(&deg[d.z], 1); if (p < BCAP) outSlots[(size_t)d.z * 256 + p] = (unsigned short)s.z;
            p = atomicAdd(&deg[d.w], 1); if (p < BCAP) outSlots[(size_t)d.w * 256 + p] = (unsigned short)s.w;
        }
    } else {
        // x -> bf16 (independent of scatter data; blocks exist only on big path)
        int i = (b - EDGE_BLOCKS) * 256 + t;  // 0 .. 799999, 8 floats each
        if (i < N_NODES * D / 8) {
            float4 a = *(const float4*)(x + (size_t)8 * i);
            float4 c = *(const float4*)(x + (size_t)8 * i + 4);
            uint4 o;
            o.x = pack2(a.x, a.y);
            o.y = pack2(a.z, a.w);
            o.z = pack2(c.x, c.y);
            o.w = pack2(c.z, c.w);
            *(uint4*)(xb + (size_t)8 * i) = o;
        }
    }
}

// ---- K2: normArr from final deg + bf16 weight split (dstbuf now dead) -------
__global__ void prep_kernel(const int* __restrict__ deg, float* __restrict__ normArr,
                            const float* __restrict__ w1, const float* __restrict__ w2,
                            unsigned short* __restrict__ whi1, unsigned short* __restrict__ wlo1,
                            unsigned short* __restrict__ whi2, unsigned short* __restrict__ wlo2) {
    int b = blockIdx.x, t = threadIdx.x;
    if (b < NORM_BLOCKS) {
        int n = b * 256 + t;
        if (n < N_NODES)
            normArr[n] = rsqrtf(fmaxf((float)deg[n], 1.0f));
    } else {
        int m = (b - NORM_BLOCKS) * 256 + t;  // 0 .. 32767
        int sel = m >> 14;  // 0: w1, 1: w2 (16384 elements each)
        int j = m & 16383;
        float v = sel ? w2[j] : w1[j];
        unsigned short h = bf_rne(v);
        unsigned short lo = bf_rne(v - bf_up(h));
        if (sel) { whi2[j] = h; wlo2[j] = lo; }
        else     { whi1[j] = h; wlo1[j] = lo; }
    }
}

// ======== MFMA MLP phase (round-7/10 proven), shared by both fused paths =====
// 4 waves: wave wv -> col 32-block cb=wv*32 (all 16 rows in the one tile).
// mfma_f32_16x16x32_bf16: A row = lane&15, k = (lane>>4)*8 + i (8 consecutive);
// B col = lane&15, same k;  D col = lane&15, row = (lane>>4)*4 + reg.
#define MLP_BODY                                                               \
    int wv = t >> 6;                                                           \
    int cb = wv << 5;                                                          \
    int l15 = l & 15;                                                          \
    int kq = l >> 4;                                                           \
    const char* phiA = (const char*)&Ahi[l15][0];                              \
    const char* ploA = (const char*)&Alo[l15][0];                              \
    v4i ahi[4], alo[4];                                                        \
_Pragma("unroll")                                                              \
    for (int kt = 0; kt < 4; ++kt) {                                           \
        int off = ((((kt << 2) | kq) ^ l15) << 4);                             \
        ahi[kt] = *(const v4i*)(phiA + off);                                   \
        alo[kt] = *(const v4i*)(ploA + off);                                   \
    }                                                                          \
    __syncthreads();                                                           \
_Pragma("unroll")                                                              \
    for (int ct = 0; ct < 2; ++ct) {                                           \
        int c = cb + (ct << 4) + l15;                                          \
        float bv = b1[c];                                                      \
        v4f acc = {bv, bv, bv, bv};                                            \
        const unsigned short* wh = whi1 + c * D + (kq << 3);                   \
        const unsigned short* wl = wlo1 + c * D + (kq << 3);                   \
_Pragma("unroll")                                                              \
        for (int kt = 0; kt < 4; ++kt) {                                       \
            v4i bh = *(const v4i*)(wh + (kt << 5));                            \
            v4i bl = *(const v4i*)(wl + (kt << 5));                            \
            asm volatile("v_mfma_f32_16x16x32_bf16 %0, %1, %2, %0" : "+v"(acc) : "v"(ahi[kt]), "v"(bh)); \
            asm volatile("v_mfma_f32_16x16x32_bf16 %0, %1, %2, %0" : "+v"(acc) : "v"(alo[kt]), "v"(bh)); \
            asm volatile("v_mfma_f32_16x16x32_bf16 %0, %1, %2, %0" : "+v"(acc) : "v"(ahi[kt]), "v"(bl)); \
        }                                                                      \
        asm volatile("s_nop 7\n\ts_nop 7" : "+v"(acc));                        \
_Pragma("unroll")                                                              \
        for (int r = 0; r < 4; ++r) {                                          \
            float v = fmaxf(acc[r], 0.0f);                                     \
            unsigned short hv = bf_rne(v);                                     \
            unsigned short lv = bf_rne(v - bf_up(hv));                         \
            int ro = (kq << 2) + r;                                            \
            int byte = (2 * c) ^ ((ro & 15) << 4);                             \
            *(unsigned short*)((char*)&Ahi[ro][0] + byte) = hv;                \
            *(unsigned short*)((char*)&Alo[ro][0] + byte) = lv;                \
        }                                                                      \
    }                                                                          \
    __syncthreads();                                                           \
_Pragma("unroll")                                                              \
    for (int kt = 0; kt < 4; ++kt) {                                           \
        int off = ((((kt << 2) | kq) ^ l15) << 4);                             \
        ahi[kt] = *(const v4i*)(phiA + off);                                   \
        alo[kt] = *(const v4i*)(ploA + off);                                   \
    }                                                                          \
_Pragma("unroll")                                                              \
    for (int ct = 0; ct < 2; ++ct) {                                           \
        int c = cb + (ct << 4) + l15;                                          \
        float bv = b2[c];                                                      \
        v4f acc = {bv, bv, bv, bv};                                            \
        const unsigned short* wh = whi2 + c * D + (kq << 3);                   \
        const unsigned short* wl = wlo2 + c * D + (kq << 3);                   \
_Pragma("unroll")                                                              \
        for (int kt = 0; kt < 4; ++kt) {                                       \
            v4i bh = *(const v4i*)(wh + (kt << 5));                            \
            v4i bl = *(const v4i*)(wl + (kt << 5));                            \
            asm volatile("v_mfma_f32_16x16x32_bf16 %0, %1, %2, %0" : "+v"(acc) : "v"(ahi[kt]), "v"(bh)); \
            asm volatile("v_mfma_f32_16x16x32_bf16 %0, %1, %2, %0" : "+v"(acc) : "v"(alo[kt]), "v"(bh)); \
            asm volatile("v_mfma_f32_16x16x32_bf16 %0, %1, %2, %0" : "+v"(acc) : "v"(ahi[kt]), "v"(bl)); \
        }                                                                      \
        asm volatile("s_nop 7\n\ts_nop 7" : "+v"(acc));                        \
_Pragma("unroll")                                                              \
        for (int r = 0; r < 4; ++r) {                                          \
            int ro = row_base + (kq << 2) + r;                                 \
            if (ro < N_NODES)                                                  \
                io[(size_t)ro * D + c] = fmaxf(acc[r], 0.0f);                  \
        }                                                                      \
    }

// -------- fused (bf16-x path): halved gather line traffic --------------------
__global__ __launch_bounds__(256) void fused_gather_mlp_bf16(
    const unsigned short* __restrict__ xb,
    const unsigned short* slotsIn,      // aliases io — NO restrict
    const float* __restrict__ normArr, const int* __restrict__ deg,
    float* io,                          // aliases slotsIn — NO restrict
    const unsigned short* __restrict__ whi1, const unsigned short* __restrict__ wlo1,
    const float* __restrict__ b1,
    const unsigned short* __restrict__ whi2, const unsigned short* __restrict__ wlo2,
    const float* __restrict__ b2) {
    __shared__ __align__(16) unsigned short Ahi[ROWS][D];  // 4 KB
    __shared__ __align__(16) unsigned short Alo[ROWS][D];  // 4 KB
    __shared__ unsigned short colsL[ROWS][LCAP];           // 2 KB
    __shared__ float ncolL[ROWS][LCAP];                    // 4 KB
    __shared__ int degL[ROWS];
    __shared__ int nextRow;
    int row_base = blockIdx.x * ROWS;
    int t = threadIdx.x;
    int tx = t & 31;   // lane in group; feature quad 4*tx..4*tx+3
    int l = t & 63;    // lane in wave

    if (t < ROWS) degL[t] = deg[row_base + t];
    if (t == ROWS) nextRow = 0;
    __syncthreads();

    for (int e2 = t; e2 < ROWS * LCAP; e2 += 256) {
        int r = e2 >> 6;
        int j = e2 & (LCAP - 1);
        if (j < degL[r]) {
            int s = slotsIn[(size_t)(row_base + r) * 256 + j];
            colsL[r][j] = (unsigned short)s;
            ncolL[r][j] = normArr[s];
        } else {
            colsL[r][j] = 0;
            ncolL[r][j] = 0.f;
        }
    }
    __syncthreads();

    // gather: 8 groups of 32 lanes, work-stealing; x rows read as bf16 (8B/lane)
    for (;;) {
        int rr;
        if (tx == 0) rr = atomicAdd(&nextRow, 1);
        rr = __shfl(rr, l & 32);
        if (rr >= ROWS) break;
        int dr = degL[rr];
        float nr = rsqrtf(fmaxf((float)dr, 1.0f));
        float4 acc = make_float4(0.f, 0.f, 0.f, 0.f);
        int jend = min(dr, LCAP);
        for (int j = 0; j < jend; j += 8) {  // zero-norm pads mask ragged tail
            int s0 = colsL[rr][j + 0], s1 = colsL[rr][j + 1], s2 = colsL[rr][j + 2], s3 = colsL[rr][j + 3];
            int s4 = colsL[rr][j + 4], s5 = colsL[rr][j + 5], s6 = colsL[rr][j + 6], s7 = colsL[rr][j + 7];
            float n0 = ncolL[rr][j + 0], n1 = ncolL[rr][j + 1], n2 = ncolL[rr][j + 2], n3 = ncolL[rr][j + 3];
            float n4 = ncolL[rr][j + 4], n5 = ncolL[rr][j + 5], n6 = ncolL[rr][j + 6], n7 = ncolL[rr][j + 7];
            uint2 v0 = *(const uint2*)(xb + (size_t)s0 * D + 4 * tx);
            uint2 v1 = *(const uint2*)(xb + (size_t)s1 * D + 4 * tx);
            uint2 v2 = *(const uint2*)(xb + (size_t)s2 * D + 4 * tx);
            uint2 v3 = *(const uint2*)(xb + (size_t)s3 * D + 4 * tx);
            uint2 v4 = *(const uint2*)(xb + (size_t)s4 * D + 4 * tx);
            uint2 v5 = *(const uint2*)(xb + (size_t)s5 * D + 4 * tx);
            uint2 v6 = *(const uint2*)(xb + (size_t)s6 * D + 4 * tx);
            uint2 v7 = *(const uint2*)(xb + (size_t)s7 * D + 4 * tx);
            acc.x += __uint_as_float(v0.x << 16) * n0 + __uint_as_float(v1.x << 16) * n1
                   + __uint_as_float(v2.x << 16) * n2 + __uint_as_float(v3.x << 16) * n3
                   + __uint_as_float(v4.x << 16) * n4 + __uint_as_float(v5.x << 16) * n5
                   + __uint_as_float(v6.x << 16) * n6 + __uint_as_float(v7.x << 16) * n7;
            acc.y += __uint_as_float(v0.x & 0xffff0000u) * n0 + __uint_as_float(v1.x & 0xffff0000u) * n1
                   + __uint_as_float(v2.x & 0xffff0000u) * n2 + __uint_as_float(v3.x & 0xffff0000u) * n3
                   + __uint_as_float(v4.x & 0xffff0000u) * n4 + __uint_as_float(v5.x & 0xffff0000u) * n5
                   + __uint_as_float(v6.x & 0xffff0000u) * n6 + __uint_as_float(v7.x & 0xffff0000u) * n7;
            acc.z += __uint_as_float(v0.y << 16) * n0 + __uint_as_float(v1.y << 16) * n1
                   + __uint_as_float(v2.y << 16) * n2 + __uint_as_float(v3.y << 16) * n3
                   + __uint_as_float(v4.y << 16) * n4 + __uint_as_float(v5.y << 16) * n5
                   + __uint_as_float(v6.y << 16) * n6 + __uint_as_float(v7.y << 16) * n7;
            acc.w += __uint_as_float(v0.y & 0xffff0000u) * n0 + __uint_as_float(v1.y & 0xffff0000u) * n1
                   + __uint_as_float(v2.y & 0xffff0000u) * n2 + __uint_as_float(v3.y & 0xffff0000u) * n3
                   + __uint_as_float(v4.y & 0xffff0000u) * n4 + __uint_as_float(v5.y & 0xffff0000u) * n5
                   + __uint_as_float(v6.y & 0xffff0000u) * n6 + __uint_as_float(v7.y & 0xffff0000u) * n7;
        }
        if (dr > LCAP) {  // essentially impossible; correctness fallback
            int je = min(dr, BCAP);
            for (int j = LCAP; j < je; ++j) {
                int s = slotsIn[(size_t)(row_base + rr) * 256 + j];
                float nv = normArr[s];
                uint2 v = *(const uint2*)(xb + (size_t)s * D + 4 * tx);
                acc.x += __uint_as_float(v.x << 16) * nv;
                acc.y += __uint_as_float(v.x & 0xffff0000u) * nv;
                acc.z += __uint_as_float(v.y << 16) * nv;
                acc.w += __uint_as_float(v.y & 0xffff0000u) * nv;
            }
        }
        acc.x *= nr; acc.y *= nr; acc.z *= nr; acc.w *= nr;
        unsigned hw0, lw0, hw1, lw1;
        split_pack(acc.x, acc.y, hw0, lw0);
        split_pack(acc.z, acc.w, hw1, lw1);
        int byte = (8 * tx) ^ ((rr & 15) << 4);
        *(uint2*)((char*)&Ahi[rr][0] + byte) = make_uint2(hw0, hw1);
        *(uint2*)((char*)&Alo[rr][0] + byte) = make_uint2(lw0, lw1);
    }
    __syncthreads();

    MLP_BODY
}

// -------- fused (f32-x fallback): round-10 proven kernel, verbatim -----------
__global__ __launch_bounds__(256) void fused_gather_mlp_f32(
    const float* __restrict__ x,
    const unsigned short* slotsIn,      // aliases io — NO restrict
    const float* __restrict__ normArr, const int* __restrict__ deg,
    float* io,                          // aliases slotsIn — NO restrict
    const unsigned short* __restrict__ whi1, const unsigned short* __restrict__ wlo1,
    const float* __restrict__ b1,
    const unsigned short* __restrict__ whi2, const unsigned short* __restrict__ wlo2,
    const float* __restrict__ b2) {
    __shared__ __align__(16) unsigned short Ahi[ROWS][D];
    __shared__ __align__(16) unsigned short Alo[ROWS][D];
    __shared__ unsigned short colsL[ROWS][LCAP];
    __shared__ float ncolL[ROWS][LCAP];
    __shared__ int degL[ROWS];
    __shared__ int nextRow;
    int row_base = blockIdx.x * ROWS;
    int t = threadIdx.x;
    int tx = t & 31;
    int l = t & 63;

    if (t < ROWS) degL[t] = deg[row_base + t];
    if (t == ROWS) nextRow = 0;
    __syncthreads();

    for (int e2 = t; e2 < ROWS * LCAP; e2 += 256) {
        int r = e2 >> 6;
        int j = e2 & (LCAP - 1);
        if (j < degL[r]) {
            int s = slotsIn[(size_t)(row_base + r) * 256 + j];
            colsL[r][j] = (unsigned short)s;
            ncolL[r][j] = normArr[s];
        } else {
            colsL[r][j] = 0;
            ncolL[r][j] = 0.f;
        }
    }
    __syncthreads();

    for (;;) {
        int rr;
        if (tx == 0) rr = atomicAdd(&nextRow, 1);
        rr = __shfl(rr, l & 32);
        if (rr >= ROWS) break;
        int dr = degL[rr];
        float nr = rsqrtf(fmaxf((float)dr, 1.0f));
        float4 acc = make_float4(0.f, 0.f, 0.f, 0.f);
        int jend = min(dr, LCAP);
        for (int j = 0; j < jend; j += 8) {
            int s0 = colsL[rr][j + 0], s1 = colsL[rr][j + 1], s2 = colsL[rr][j + 2], s3 = colsL[rr][j + 3];
            int s4 = colsL[rr][j + 4], s5 = colsL[rr][j + 5], s6 = colsL[rr][j + 6], s7 = colsL[rr][j + 7];
            float n0 = ncolL[rr][j + 0], n1 = ncolL[rr][j + 1], n2 = ncolL[rr][j + 2], n3 = ncolL[rr][j + 3];
            float n4 = ncolL[rr][j + 4], n5 = ncolL[rr][j + 5], n6 = ncolL[rr][j + 6], n7 = ncolL[rr][j + 7];
            float4 x0 = *(const float4*)(x + (size_t)s0 * D + 4 * tx);
            float4 x1 = *(const float4*)(x + (size_t)s1 * D + 4 * tx);
            float4 x2 = *(const float4*)(x + (size_t)s2 * D + 4 * tx);
            float4 x3 = *(const float4*)(x + (size_t)s3 * D + 4 * tx);
            float4 x4 = *(const float4*)(x + (size_t)s4 * D + 4 * tx);
            float4 x5 = *(const float4*)(x + (size_t)s5 * D + 4 * tx);
            float4 x6 = *(const float4*)(x + (size_t)s6 * D + 4 * tx);
            float4 x7 = *(const float4*)(x + (size_t)s7 * D + 4 * tx);
            acc.x += x0.x * n0 + x1.x * n1 + x2.x * n2 + x3.x * n3
                   + x4.x * n4 + x5.x * n5 + x6.x * n6 + x7.x * n7;
            acc.y += x0.y * n0 + x1.y * n1 + x2.y * n2 + x3.y * n3
                   + x4.y * n4 + x5.y * n5 + x6.y * n6 + x7.y * n7;
            acc.z += x0.z * n0 + x1.z * n1 + x2.z * n2 + x3.z * n3
                   + x4.z * n4 + x5.z * n5 + x6.z * n6 + x7.z * n7;
            acc.w += x0.w * n0 + x1.w * n1 + x2.w * n2 + x3.w * n3
                   + x4.w * n4 + x5.w * n5 + x6.w * n6 + x7.w * n7;
        }
        if (dr > LCAP) {
            int je = min(dr, BCAP);
            for (int j = LCAP; j < je; ++j) {
                int s = slotsIn[(size_t)(row_base + rr) * 256 + j];
                float nv = normArr[s];
                float4 xv = *(const float4*)(x + (size_t)s * D + 4 * tx);
                acc.x += xv.x * nv; acc.y += xv.y * nv;
                acc.z += xv.z * nv; acc.w += xv.w * nv;
            }
        }
        acc.x *= nr; acc.y *= nr; acc.z *= nr; acc.w *= nr;
        unsigned hw0, lw0, hw1, lw1;
        split_pack(acc.x, acc.y, hw0, lw0);
        split_pack(acc.z, acc.w, hw1, lw1);
        int byte = (8 * tx) ^ ((rr & 15) << 4);
        *(uint2*)((char*)&Ahi[rr][0] + byte) = make_uint2(hw0, hw1);
        *(uint2*)((char*)&Alo[rr][0] + byte) = make_uint2(lw0, lw1);
    }
    __syncthreads();

    MLP_BODY
}

extern "C" void kernel_launch(void* const* d_in, const int* in_sizes, int n_in,
                              void* d_out, int out_size, void* d_ws, size_t ws_size,
                              hipStream_t stream) {
    const float* x      = (const float*)d_in[0];
    const int*   src    = (const int*)d_in[1];
    int*         dstbuf = (int*)d_in[2];   // dead after scatter -> scratch for K2
    const float* w_conv = (const float*)d_in[3];
    const float* b_conv = (const float*)d_in[4];
    const float* w_lin  = (const float*)d_in[5];
    const float* b_lin  = (const float*)d_in[6];

    int* deg = (int*)d_ws;  // 200,000 B (known-safe size)
    float* normArr = (float*)dstbuf;
    unsigned short* whi1 = (unsigned short*)((char*)dstbuf + 200000);
    unsigned short* wlo1 = (unsigned short*)((char*)dstbuf + 232768);
    unsigned short* whi2 = (unsigned short*)((char*)dstbuf + 265536);
    unsigned short* wlo2 = (unsigned short*)((char*)dstbuf + 298304);
    unsigned short* xb = (unsigned short*)((char*)d_ws + XB_OFF);
    const bool big = ws_size >= WS_NEEDED;  // bf16-x plane fits in workspace?

    hipMemsetAsync(deg, 0, (size_t)N_NODES * sizeof(int), stream);
    scatter_kernel<<<EDGE_BLOCKS + (big ? XCONV_BLOCKS : 0), 256, 0, stream>>>(
        (const int4*)src, (const int4*)dstbuf, deg, (unsigned short*)d_out, x, xb);
    prep_kernel<<<NORM_BLOCKS + WSPLIT_BLOCKS, 256, 0, stream>>>(
        deg, normArr, w_conv, w_lin, whi1, wlo1, whi2, wlo2);
    if (big) {
        fused_gather_mlp_bf16<<<N_NODES / ROWS, 256, 0, stream>>>(
            xb, (const unsigned short*)d_out, normArr, deg, (float*)d_out,
            whi1, wlo1, b_conv, whi2, wlo2, b_lin);
    } else {
        fused_gather_mlp_f32<<<N_NODES / ROWS, 256, 0, stream>>>(
            x, (const unsigned short*)d_out, normArr, deg, (float*)d_out,
            whi1, wlo1, b_conv, whi2, wlo2, b_lin);
    }
}

// Round 12
// 204.599 us; speedup vs baseline: 1.0644x; 1.0644x over previous
//
#include <hip/hip_runtime.h>

#define N_NODES 50000
#define N_EDGES 800000
#define D 128
#define ROWS 16
#define BCAP 255          // slot cap within a row's 512B out budget (deg max ~40)
#define LCAP 64           // LDS-staged slots per row, power of 2 (P(deg>64) ~ 0)
#define ESC_BLOCKS 3125   // 1 edge/thread: 3125*256 = 800000 exactly
#define XCONV_BLOCKS 3125 // 3125*256*8 = 6.4M floats = x converted to bf16
#define NORM_BLOCKS 196   // fallback path only
#define WSPLIT_BLOCKS 128 // 128*256 = 32768 = 2*D*D
#define XB_OFF 200064     // xb offset in d_ws (16B aligned, past deg)
#define WHI_OFF 13000064  // weight planes in d_ws, past xb (big path)
#define WS_NEEDED 13131136ull

typedef int   v4i __attribute__((ext_vector_type(4)));
typedef float v4f __attribute__((ext_vector_type(4)));

// Buffer map (big path, ws_size >= WS_NEEDED):
//  d_ws [0, 200000)          : deg (int[50000]) — cursor == final in-degree
//  d_ws [200064, +12.8M)     : xb (bf16 copy of x)
//  d_ws [13000064, +131072)  : whi1/wlo1/whi2/wlo2 (bf16 hi/lo weight planes)
//  d_out                     : per-row 512B: scatter writes src ids (ushort);
//                              fused reads ONLY ITS OWN rows' slots, then
//                              overwrites them => no cross-block hazard.
// Fallback (small ws): round-10 pipeline — normArr+weights in dstbuf, f32 x.
// Round-9 lesson: MFMA B operands come from MEMORY loads only (waitcnt slack).

// ---- round-to-nearest-even f32 -> bf16 helpers ------------------------------
__device__ __forceinline__ unsigned short bf_rne(float v) {
    unsigned u = __float_as_uint(v);
    u += 0x7FFFu + ((u >> 16) & 1u);
    return (unsigned short)(u >> 16);
}
__device__ __forceinline__ float bf_up(unsigned short h) {
    return __uint_as_float((unsigned)h << 16);
}
__device__ __forceinline__ void split_pack(float a, float b, unsigned& hw, unsigned& lw) {
    unsigned short ha = bf_rne(a);
    unsigned short hb = bf_rne(b);
    unsigned short la = bf_rne(a - bf_up(ha));
    unsigned short lb = bf_rne(b - bf_up(hb));
    hw = (unsigned)ha | ((unsigned)hb << 16);
    lw = (unsigned)la | ((unsigned)lb << 16);
}
__device__ __forceinline__ unsigned pack2(float a, float b) {
    return (unsigned)bf_rne(a) | ((unsigned)bf_rne(b) << 16);
}

// ---- K1: 1-edge/thread scatter + x->bf16 conv + weight split (big path) -----
__global__ void scatter_kernel(const int* __restrict__ src, const int* __restrict__ dst,
                               int* __restrict__ deg, unsigned short* outSlots,
                               const float* __restrict__ x, unsigned short* __restrict__ xb,
                               const float* __restrict__ w1, const float* __restrict__ w2,
                               unsigned short* __restrict__ whi1, unsigned short* __restrict__ wlo1,
                               unsigned short* __restrict__ whi2, unsigned short* __restrict__ wlo2) {
    int b = blockIdx.x, t = threadIdx.x;
    if (b < ESC_BLOCKS) {
        int e = b * 256 + t;  // 3125*256 == N_EDGES exactly
        int s = src[e], d = dst[e];
        int p = atomicAdd(&deg[d], 1);
        if (p < BCAP) outSlots[(size_t)d * 256 + p] = (unsigned short)s;
    } else if (b < ESC_BLOCKS + XCONV_BLOCKS) {
        int i = (b - ESC_BLOCKS) * 256 + t;  // 8 floats each
        float4 a = *(const float4*)(x + (size_t)8 * i);
        float4 c = *(const float4*)(x + (size_t)8 * i + 4);
        uint4 o;
        o.x = pack2(a.x, a.y);
        o.y = pack2(a.z, a.w);
        o.z = pack2(c.x, c.y);
        o.w = pack2(c.z, c.w);
        *(uint4*)(xb + (size_t)8 * i) = o;
    } else {
        int m = (b - ESC_BLOCKS - XCONV_BLOCKS) * 256 + t;  // 0 .. 32767
        int sel = m >> 14;  // 0: w1, 1: w2
        int j = m & 16383;
        float v = sel ? w2[j] : w1[j];
        unsigned short h = bf_rne(v);
        unsigned short lo = bf_rne(v - bf_up(h));
        if (sel) { whi2[j] = h; wlo2[j] = lo; }
        else     { whi1[j] = h; wlo1[j] = lo; }
    }
}

// ---- prep (FALLBACK path only): normArr + weight split into dstbuf ----------
__global__ void prep_kernel(const int* __restrict__ deg, float* __restrict__ normArr,
                            const float* __restrict__ w1, const float* __restrict__ w2,
                            unsigned short* __restrict__ whi1, unsigned short* __restrict__ wlo1,
                            unsigned short* __restrict__ whi2, unsigned short* __restrict__ wlo2) {
    int b = blockIdx.x, t = threadIdx.x;
    if (b < NORM_BLOCKS) {
        int n = b * 256 + t;
        if (n < N_NODES)
            normArr[n] = rsqrtf(fmaxf((float)deg[n], 1.0f));
    } else {
        int m = (b - NORM_BLOCKS) * 256 + t;
        int sel = m >> 14;
        int j = m & 16383;
        float v = sel ? w2[j] : w1[j];
        unsigned short h = bf_rne(v);
        unsigned short lo = bf_rne(v - bf_up(h));
        if (sel) { whi2[j] = h; wlo2[j] = lo; }
        else     { whi1[j] = h; wlo1[j] = lo; }
    }
}

// ======== MFMA MLP phase (round-7/10 proven), shared by both fused paths =====
// 4 waves: wave wv -> col 32-block cb=wv*32 (all 16 rows in the one tile).
// mfma_f32_16x16x32_bf16: A row = lane&15, k = (lane>>4)*8 + i (8 consecutive);
// B col = lane&15, same k;  D col = lane&15, row = (lane>>4)*4 + reg.
#define MLP_BODY                                                               \
    int wv = t >> 6;                                                           \
    int cb = wv << 5;                                                          \
    int l15 = l & 15;                                                          \
    int kq = l >> 4;                                                           \
    const char* phiA = (const char*)&Ahi[l15][0];                              \
    const char* ploA = (const char*)&Alo[l15][0];                              \
    v4i ahi[4], alo[4];                                                        \
_Pragma("unroll")                                                              \
    for (int kt = 0; kt < 4; ++kt) {                                           \
        int off = ((((kt << 2) | kq) ^ l15) << 4);                             \
        ahi[kt] = *(const v4i*)(phiA + off);                                   \
        alo[kt] = *(const v4i*)(ploA + off);                                   \
    }                                                                          \
    __syncthreads();                                                           \
_Pragma("unroll")                                                              \
    for (int ct = 0; ct < 2; ++ct) {                                           \
        int c = cb + (ct << 4) + l15;                                          \
        float bv = b1[c];                                                      \
        v4f acc = {bv, bv, bv, bv};                                            \
        const unsigned short* wh = whi1 + c * D + (kq << 3);                   \
        const unsigned short* wl = wlo1 + c * D + (kq << 3);                   \
_Pragma("unroll")                                                              \
        for (int kt = 0; kt < 4; ++kt) {                                       \
            v4i bh = *(const v4i*)(wh + (kt << 5));                            \
            v4i bl = *(const v4i*)(wl + (kt << 5));                            \
            asm volatile("v_mfma_f32_16x16x32_bf16 %0, %1, %2, %0" : "+v"(acc) : "v"(ahi[kt]), "v"(bh)); \
            asm volatile("v_mfma_f32_16x16x32_bf16 %0, %1, %2, %0" : "+v"(acc) : "v"(alo[kt]), "v"(bh)); \
            asm volatile("v_mfma_f32_16x16x32_bf16 %0, %1, %2, %0" : "+v"(acc) : "v"(ahi[kt]), "v"(bl)); \
        }                                                                      \
        asm volatile("s_nop 7\n\ts_nop 7" : "+v"(acc));                        \
_Pragma("unroll")                                                              \
        for (int r = 0; r < 4; ++r) {                                          \
            float v = fmaxf(acc[r], 0.0f);                                     \
            unsigned short hv = bf_rne(v);                                     \
            unsigned short lv = bf_rne(v - bf_up(hv));                         \
            int ro = (kq << 2) + r;                                            \
            int byte = (2 * c) ^ ((ro & 15) << 4);                             \
            *(unsigned short*)((char*)&Ahi[ro][0] + byte) = hv;                \
            *(unsigned short*)((char*)&Alo[ro][0] + byte) = lv;                \
        }                                                                      \
    }                                                                          \
    __syncthreads();                                                           \
_Pragma("unroll")                                                              \
    for (int kt = 0; kt < 4; ++kt) {                                           \
        int off = ((((kt << 2) | kq) ^ l15) << 4);                             \
        ahi[kt] = *(const v4i*)(phiA + off);                                   \
        alo[kt] = *(const v4i*)(ploA + off);                                   \
    }                                                                          \
_Pragma("unroll")                                                              \
    for (int ct = 0; ct < 2; ++ct) {                                           \
        int c = cb + (ct << 4) + l15;                                          \
        float bv = b2[c];                                                      \
        v4f acc = {bv, bv, bv, bv};                                            \
        const unsigned short* wh = whi2 + c * D + (kq << 3);                   \
        const unsigned short* wl = wlo2 + c * D + (kq << 3);                   \
_Pragma("unroll")                                                              \
        for (int kt = 0; kt < 4; ++kt) {                                       \
            v4i bh = *(const v4i*)(wh + (kt << 5));                            \
            v4i bl = *(const v4i*)(wl + (kt << 5));                            \
            asm volatile("v_mfma_f32_16x16x32_bf16 %0, %1, %2, %0" : "+v"(acc) : "v"(ahi[kt]), "v"(bh)); \
            asm volatile("v_mfma_f32_16x16x32_bf16 %0, %1, %2, %0" : "+v"(acc) : "v"(alo[kt]), "v"(bh)); \
            asm volatile("v_mfma_f32_16x16x32_bf16 %0, %1, %2, %0" : "+v"(acc) : "v"(ahi[kt]), "v"(bl)); \
        }                                                                      \
        asm volatile("s_nop 7\n\ts_nop 7" : "+v"(acc));                        \
_Pragma("unroll")                                                              \
        for (int r = 0; r < 4; ++r) {                                          \
            int ro = row_base + (kq << 2) + r;                                 \
            if (ro < N_NODES)                                                  \
                io[(size_t)ro * D + c] = fmaxf(acc[r], 0.0f);                  \
        }                                                                      \
    }

// -------- fused (bf16-x path): inline src norms, no normArr ------------------
__global__ __launch_bounds__(256) void fused_gather_mlp_bf16(
    const unsigned short* __restrict__ xb,
    const unsigned short* slotsIn,      // aliases io — NO restrict
    const int* __restrict__ deg,
    float* io,                          // aliases slotsIn — NO restrict
    const unsigned short* __restrict__ whi1, const unsigned short* __restrict__ wlo1,
    const float* __restrict__ b1,
    const unsigned short* __restrict__ whi2, const unsigned short* __restrict__ wlo2,
    const float* __restrict__ b2) {
    __shared__ __align__(16) unsigned short Ahi[ROWS][D];  // 4 KB
    __shared__ __align__(16) unsigned short Alo[ROWS][D];  // 4 KB
    __shared__ unsigned short colsL[ROWS][LCAP];           // 2 KB
    __shared__ float ncolL[ROWS][LCAP];                    // 4 KB
    __shared__ int degL[ROWS];
    __shared__ int nextRow;
    int row_base = blockIdx.x * ROWS;
    int t = threadIdx.x;
    int tx = t & 31;   // lane in group; feature quad 4*tx..4*tx+3
    int l = t & 63;    // lane in wave

    if (t < ROWS) degL[t] = deg[row_base + t];
    if (t == ROWS) nextRow = 0;
    __syncthreads();

    // stage slots + src norms (rsqrt computed inline from deg — no normArr)
    for (int e2 = t; e2 < ROWS * LCAP; e2 += 256) {
        int r = e2 >> 6;
        int j = e2 & (LCAP - 1);
        if (j < degL[r]) {
            int s = slotsIn[(size_t)(row_base + r) * 256 + j];
            colsL[r][j] = (unsigned short)s;
            ncolL[r][j] = rsqrtf(fmaxf((float)deg[s], 1.0f));
        } else {
            colsL[r][j] = 0;
            ncolL[r][j] = 0.f;
        }
    }
    __syncthreads();

    // gather: 8 groups of 32 lanes, work-stealing; x rows read as bf16 (8B/lane)
    for (;;) {
        int rr;
        if (tx == 0) rr = atomicAdd(&nextRow, 1);
        rr = __shfl(rr, l & 32);
        if (rr >= ROWS) break;
        int dr = degL[rr];
        float nr = rsqrtf(fmaxf((float)dr, 1.0f));
        float4 acc = make_float4(0.f, 0.f, 0.f, 0.f);
        int jend = min(dr, LCAP);
        for (int j = 0; j < jend; j += 8) {  // zero-norm pads mask ragged tail
            int s0 = colsL[rr][j + 0], s1 = colsL[rr][j + 1], s2 = colsL[rr][j + 2], s3 = colsL[rr][j + 3];
            int s4 = colsL[rr][j + 4], s5 = colsL[rr][j + 5], s6 = colsL[rr][j + 6], s7 = colsL[rr][j + 7];
            float n0 = ncolL[rr][j + 0], n1 = ncolL[rr][j + 1], n2 = ncolL[rr][j + 2], n3 = ncolL[rr][j + 3];
            float n4 = ncolL[rr][j + 4], n5 = ncolL[rr][j + 5], n6 = ncolL[rr][j + 6], n7 = ncolL[rr][j + 7];
            uint2 v0 = *(const uint2*)(xb + (size_t)s0 * D + 4 * tx);
            uint2 v1 = *(const uint2*)(xb + (size_t)s1 * D + 4 * tx);
            uint2 v2 = *(const uint2*)(xb + (size_t)s2 * D + 4 * tx);
            uint2 v3 = *(const uint2*)(xb + (size_t)s3 * D + 4 * tx);
            uint2 v4 = *(const uint2*)(xb + (size_t)s4 * D + 4 * tx);
            uint2 v5 = *(const uint2*)(xb + (size_t)s5 * D + 4 * tx);
            uint2 v6 = *(const uint2*)(xb + (size_t)s6 * D + 4 * tx);
            uint2 v7 = *(const uint2*)(xb + (size_t)s7 * D + 4 * tx);
            acc.x += __uint_as_float(v0.x << 16) * n0 + __uint_as_float(v1.x << 16) * n1
                   + __uint_as_float(v2.x << 16) * n2 + __uint_as_float(v3.x << 16) * n3
                   + __uint_as_float(v4.x << 16) * n4 + __uint_as_float(v5.x << 16) * n5
                   + __uint_as_float(v6.x << 16) * n6 + __uint_as_float(v7.x << 16) * n7;
            acc.y += __uint_as_float(v0.x & 0xffff0000u) * n0 + __uint_as_float(v1.x & 0xffff0000u) * n1
                   + __uint_as_float(v2.x & 0xffff0000u) * n2 + __uint_as_float(v3.x & 0xffff0000u) * n3
                   + __uint_as_float(v4.x & 0xffff0000u) * n4 + __uint_as_float(v5.x & 0xffff0000u) * n5
                   + __uint_as_float(v6.x & 0xffff0000u) * n6 + __uint_as_float(v7.x & 0xffff0000u) * n7;
            acc.z += __uint_as_float(v0.y << 16) * n0 + __uint_as_float(v1.y << 16) * n1
                   + __uint_as_float(v2.y << 16) * n2 + __uint_as_float(v3.y << 16) * n3
                   + __uint_as_float(v4.y << 16) * n4 + __uint_as_float(v5.y << 16) * n5
                   + __uint_as_float(v6.y << 16) * n6 + __uint_as_float(v7.y << 16) * n7;
            acc.w += __uint_as_float(v0.y & 0xffff0000u) * n0 + __uint_as_float(v1.y & 0xffff0000u) * n1
                   + __uint_as_float(v2.y & 0xffff0000u) * n2 + __uint_as_float(v3.y & 0xffff0000u) * n3
                   + __uint_as_float(v4.y & 0xffff0000u) * n4 + __uint_as_float(v5.y & 0xffff0000u) * n5
                   + __uint_as_float(v6.y & 0xffff0000u) * n6 + __uint_as_float(v7.y & 0xffff0000u) * n7;
        }
        if (dr > LCAP) {  // essentially impossible; correctness fallback
            int je = min(dr, BCAP);
            for (int j = LCAP; j < je; ++j) {
                int s = slotsIn[(size_t)(row_base + rr) * 256 + j];
                float nv = rsqrtf(fmaxf((float)deg[s], 1.0f));
                uint2 v = *(const uint2*)(xb + (size_t)s * D + 4 * tx);
                acc.x += __uint_as_float(v.x << 16) * nv;
                acc.y += __uint_as_float(v.x & 0xffff0000u) * nv;
                acc.z += __uint_as_float(v.y << 16) * nv;
                acc.w += __uint_as_float(v.y & 0xffff0000u) * nv;
            }
        }
        acc.x *= nr; acc.y *= nr; acc.z *= nr; acc.w *= nr;
        unsigned hw0, lw0, hw1, lw1;
        split_pack(acc.x, acc.y, hw0, lw0);
        split_pack(acc.z, acc.w, hw1, lw1);
        int byte = (8 * tx) ^ ((rr & 15) << 4);
        *(uint2*)((char*)&Ahi[rr][0] + byte) = make_uint2(hw0, hw1);
        *(uint2*)((char*)&Alo[rr][0] + byte) = make_uint2(lw0, lw1);
    }
    __syncthreads();

    MLP_BODY
}

// -------- fused (f32-x fallback): round-10 proven kernel, verbatim -----------
__global__ __launch_bounds__(256) void fused_gather_mlp_f32(
    const float* __restrict__ x,
    const unsigned short* slotsIn,      // aliases io — NO restrict
    const float* __restrict__ normArr, const int* __restrict__ deg,
    float* io,                          // aliases slotsIn — NO restrict
    const unsigned short* __restrict__ whi1, const unsigned short* __restrict__ wlo1,
    const float* __restrict__ b1,
    const unsigned short* __restrict__ whi2, const unsigned short* __restrict__ wlo2,
    const float* __restrict__ b2) {
    __shared__ __align__(16) unsigned short Ahi[ROWS][D];
    __shared__ __align__(16) unsigned short Alo[ROWS][D];
    __shared__ unsigned short colsL[ROWS][LCAP];
    __shared__ float ncolL[ROWS][LCAP];
    __shared__ int degL[ROWS];
    __shared__ int nextRow;
    int row_base = blockIdx.x * ROWS;
    int t = threadIdx.x;
    int tx = t & 31;
    int l = t & 63;

    if (t < ROWS) degL[t] = deg[row_base + t];
    if (t == ROWS) nextRow = 0;
    __syncthreads();

    for (int e2 = t; e2 < ROWS * LCAP; e2 += 256) {
        int r = e2 >> 6;
        int j = e2 & (LCAP - 1);
        if (j < degL[r]) {
            int s = slotsIn[(size_t)(row_base + r) * 256 + j];
            colsL[r][j] = (unsigned short)s;
            ncolL[r][j] = normArr[s];
        } else {
            colsL[r][j] = 0;
            ncolL[r][j] = 0.f;
        }
    }
    __syncthreads();

    for (;;) {
        int rr;
        if (tx == 0) rr = atomicAdd(&nextRow, 1);
        rr = __shfl(rr, l & 32);
        if (rr >= ROWS) break;
        int dr = degL[rr];
        float nr = rsqrtf(fmaxf((float)dr, 1.0f));
        float4 acc = make_float4(0.f, 0.f, 0.f, 0.f);
        int jend = min(dr, LCAP);
        for (int j = 0; j < jend; j += 8) {
            int s0 = colsL[rr][j + 0], s1 = colsL[rr][j + 1], s2 = colsL[rr][j + 2], s3 = colsL[rr][j + 3];
            int s4 = colsL[rr][j + 4], s5 = colsL[rr][j + 5], s6 = colsL[rr][j + 6], s7 = colsL[rr][j + 7];
            float n0 = ncolL[rr][j + 0], n1 = ncolL[rr][j + 1], n2 = ncolL[rr][j + 2], n3 = ncolL[rr][j + 3];
            float n4 = ncolL[rr][j + 4], n5 = ncolL[rr][j + 5], n6 = ncolL[rr][j + 6], n7 = ncolL[rr][j + 7];
            float4 x0 = *(const float4*)(x + (size_t)s0 * D + 4 * tx);
            float4 x1 = *(const float4*)(x + (size_t)s1 * D + 4 * tx);
            float4 x2 = *(const float4*)(x + (size_t)s2 * D + 4 * tx);
            float4 x3 = *(const float4*)(x + (size_t)s3 * D + 4 * tx);
            float4 x4 = *(const float4*)(x + (size_t)s4 * D + 4 * tx);
            float4 x5 = *(const float4*)(x + (size_t)s5 * D + 4 * tx);
            float4 x6 = *(const float4*)(x + (size_t)s6 * D + 4 * tx);
            float4 x7 = *(const float4*)(x + (size_t)s7 * D + 4 * tx);
            acc.x += x0.x * n0 + x1.x * n1 + x2.x * n2 + x3.x * n3
                   + x4.x * n4 + x5.x * n5 + x6.x * n6 + x7.x * n7;
            acc.y += x0.y * n0 + x1.y * n1 + x2.y * n2 + x3.y * n3
                   + x4.y * n4 + x5.y * n5 + x6.y * n6 + x7.y * n7;
            acc.z += x0.z * n0 + x1.z * n1 + x2.z * n2 + x3.z * n3
                   + x4.z * n4 + x5.z * n5 + x6.z * n6 + x7.z * n7;
            acc.w += x0.w * n0 + x1.w * n1 + x2.w * n2 + x3.w * n3
                   + x4.w * n4 + x5.w * n5 + x6.w * n6 + x7.w * n7;
        }
        if (dr > LCAP) {
            int je = min(dr, BCAP);
            for (int j = LCAP; j < je; ++j) {
                int s = slotsIn[(size_t)(row_base + rr) * 256 + j];
                float nv = normArr[s];
                float4 xv = *(const float4*)(x + (size_t)s * D + 4 * tx);
                acc.x += xv.x * nv; acc.y += xv.y * nv;
                acc.z += xv.z * nv; acc.w += xv.w * nv;
            }
        }
        acc.x *= nr; acc.y *= nr; acc.z *= nr; acc.w *= nr;
        unsigned hw0, lw0, hw1, lw1;
        split_pack(acc.x, acc.y, hw0, lw0);
        split_pack(acc.z, acc.w, hw1, lw1);
        int byte = (8 * tx) ^ ((rr & 15) << 4);
        *(uint2*)((char*)&Ahi[rr][0] + byte) = make_uint2(hw0, hw1);
        *(uint2*)((char*)&Alo[rr][0] + byte) = make_uint2(lw0, lw1);
    }
    __syncthreads();

    MLP_BODY
}

extern "C" void kernel_launch(void* const* d_in, const int* in_sizes, int n_in,
                              void* d_out, int out_size, void* d_ws, size_t ws_size,
                              hipStream_t stream) {
    const float* x      = (const float*)d_in[0];
    const int*   src    = (const int*)d_in[1];
    int*         dstbuf = (int*)d_in[2];   // fallback: dead after scatter
    const float* w_conv = (const float*)d_in[3];
    const float* b_conv = (const float*)d_in[4];
    const float* w_lin  = (const float*)d_in[5];
    const float* b_lin  = (const float*)d_in[6];

    int* deg = (int*)d_ws;  // 200,000 B (known-safe size)
    unsigned short* xb = (unsigned short*)((char*)d_ws + XB_OFF);
    const bool big = ws_size >= WS_NEEDED;

    hipMemsetAsync(deg, 0, (size_t)N_NODES * sizeof(int), stream);
    if (big) {
        // weight planes live in d_ws past xb
        unsigned short* whi1 = (unsigned short*)((char*)d_ws + WHI_OFF);
        unsigned short* wlo1 = (unsigned short*)((char*)d_ws + WHI_OFF + 32768);
        unsigned short* whi2 = (unsigned short*)((char*)d_ws + WHI_OFF + 65536);
        unsigned short* wlo2 = (unsigned short*)((char*)d_ws + WHI_OFF + 98304);
        scatter_kernel<<<ESC_BLOCKS + XCONV_BLOCKS + WSPLIT_BLOCKS, 256, 0, stream>>>(
            src, (const int*)dstbuf, deg, (unsigned short*)d_out, x, xb,
            w_conv, w_lin, whi1, wlo1, whi2, wlo2);
        fused_gather_mlp_bf16<<<N_NODES / ROWS, 256, 0, stream>>>(
            xb, (const unsigned short*)d_out, deg, (float*)d_out,
            whi1, wlo1, b_conv, whi2, wlo2, b_lin);
    } else {
        // round-10 proven fallback: normArr + weights in dstbuf (dead after scatter)
        float* normArr = (float*)dstbuf;
        unsigned short* whi1 = (unsigned short*)((char*)dstbuf + 200000);
        unsigned short* wlo1 = (unsigned short*)((char*)dstbuf + 232768);
        unsigned short* whi2 = (unsigned short*)((char*)dstbuf + 265536);
        unsigned short* wlo2 = (unsigned short*)((char*)dstbuf + 298304);
        scatter_kernel<<<ESC_BLOCKS, 256, 0, stream>>>(
            src, (const int*)dstbuf, deg, (unsigned short*)d_out, x, xb,
            w_conv, w_lin, whi1, wlo1, whi2, wlo2);
        prep_kernel<<<NORM_BLOCKS + WSPLIT_BLOCKS, 256, 0, stream>>>(
            deg, normArr, w_conv, w_lin, whi1, wlo1, whi2, wlo2);
        fused_gather_mlp_f32<<<N_NODES / ROWS, 256, 0, stream>>>(
            x, (const unsigned short*)d_out, normArr, deg, (float*)d_out,
            whi1, wlo1, b_conv, whi2, wlo2, b_lin);
    }
}